// Round 7
// baseline (469.624 us; speedup 1.0000x reference)
//
#include <hip/hip_runtime.h>
#include <math.h>

#define NNODE 50000
#define NEDGE 800000
#define NBLK 196   // ceil(50000/256)

__device__ __forceinline__ float wsum64(float v) {
    #pragma unroll
    for (int m = 32; m >= 1; m >>= 1) v += __shfl_xor(v, m, 64);
    return v;
}

__device__ __forceinline__ float gelu_exact(float x) {
    return 0.5f * x * (1.0f + erff(x * 0.70710678118654752f));
}

// 8-channel GATv2 score partial: sum lrelu(x + xr + a*we) * at
__device__ __forceinline__ float part8(float4 xa, float4 xb, float a,
                                       float4 we0, float4 we1,
                                       float4 at0, float4 at1,
                                       float4 xr0, float4 xr1) {
    float z0 = fmaf(a, we0.x, xa.x + xr0.x);
    float z1 = fmaf(a, we0.y, xa.y + xr0.y);
    float z2 = fmaf(a, we0.z, xa.z + xr0.z);
    float z3 = fmaf(a, we0.w, xa.w + xr0.w);
    float z4 = fmaf(a, we1.x, xb.x + xr1.x);
    float z5 = fmaf(a, we1.y, xb.y + xr1.y);
    float z6 = fmaf(a, we1.z, xb.z + xr1.z);
    float z7 = fmaf(a, we1.w, xb.w + xr1.w);
    float s01 = fmaxf(z0, 0.2f * z0) * at0.x + fmaxf(z1, 0.2f * z1) * at0.y;
    float s23 = fmaxf(z2, 0.2f * z2) * at0.z + fmaxf(z3, 0.2f * z3) * at0.w;
    float s45 = fmaxf(z4, 0.2f * z4) * at1.x + fmaxf(z5, 0.2f * z5) * at1.y;
    float s67 = fmaxf(z6, 0.2f * z6) * at1.z + fmaxf(z7, 0.2f * z7) * at1.w;
    return (s01 + s23) + (s45 + s67);
}

// branchless-per-lane, wave-uniform-branch defer-max online softmax update
#define ONLINE_UPDATE(part, xa, xb)                                        \
    if (__any((part) > m + 8.f)) {                                         \
        float mn = fmaxf(m, (part));                                       \
        float sc = __expf(m - mn);                                         \
        float p  = __expf((part) - mn);                                    \
        den = den * sc + p;                                                \
        oa.x = oa.x * sc + p * (xa).x; oa.y = oa.y * sc + p * (xa).y;      \
        oa.z = oa.z * sc + p * (xa).z; oa.w = oa.w * sc + p * (xa).w;      \
        ob.x = ob.x * sc + p * (xb).x; ob.y = ob.y * sc + p * (xb).y;      \
        ob.z = ob.z * sc + p * (xb).z; ob.w = ob.w * sc + p * (xb).w;      \
        m = mn;                                                            \
    } else {                                                               \
        float p = __expf((part) - m);                                      \
        den += p;                                                          \
        oa.x = fmaf(p, (xa).x, oa.x); oa.y = fmaf(p, (xa).y, oa.y);        \
        oa.z = fmaf(p, (xa).z, oa.z); oa.w = fmaf(p, (xa).w, oa.w);        \
        ob.x = fmaf(p, (xb).x, ob.x); ob.y = fmaf(p, (xb).y, ob.y);        \
        ob.z = fmaf(p, (xb).z, ob.z); ob.w = fmaf(p, (xb).w, ob.w);        \
    }

// merge softmax states across lanes at xor-distance D
#define MERGE_STATE(D)                                                     \
    {                                                                      \
        float m2 = __shfl_xor(m, D, 64);                                   \
        float d2 = __shfl_xor(den, D, 64);                                 \
        float4 pa, pb;                                                     \
        pa.x = __shfl_xor(oa.x, D, 64); pa.y = __shfl_xor(oa.y, D, 64);    \
        pa.z = __shfl_xor(oa.z, D, 64); pa.w = __shfl_xor(oa.w, D, 64);    \
        pb.x = __shfl_xor(ob.x, D, 64); pb.y = __shfl_xor(ob.y, D, 64);    \
        pb.z = __shfl_xor(ob.z, D, 64); pb.w = __shfl_xor(ob.w, D, 64);    \
        float mn = fmaxf(m, m2);                                           \
        float s1 = __expf(m - mn), s2 = __expf(m2 - mn);                   \
        den = den * s1 + d2 * s2;                                          \
        oa.x = oa.x * s1 + pa.x * s2; oa.y = oa.y * s1 + pa.y * s2;        \
        oa.z = oa.z * s1 + pa.z * s2; oa.w = oa.w * s1 + pa.w * s2;        \
        ob.x = ob.x * s1 + pb.x * s2; ob.y = ob.y * s1 + pb.y * s2;        \
        ob.z = ob.z * s1 + pb.z * s2; ob.w = ob.w * s1 + pb.w * s2;        \
        m = mn;                                                            \
    }

// ---------------- utility ----------------
__global__ void fill_u32(unsigned* __restrict__ p, unsigned v, int n) {
    int i = blockIdx.x * blockDim.x + threadIdx.x;
    if (i < n) p[i] = v;
}

// ---------------- CSR build ----------------
__global__ __launch_bounds__(256) void build_deg(const int* __restrict__ ei, int* __restrict__ deg) {
    int e = blockIdx.x * 256 + threadIdx.x;
    if (e >= NEDGE) return;
    atomicAdd(&deg[ei[NEDGE + e]], 1);
}

// single-block full exclusive scan of deg[NNODE] -> base, cursor
__global__ __launch_bounds__(256) void scan_all(const int* __restrict__ deg,
                                                int* __restrict__ base,
                                                int* __restrict__ cursor) {
    __shared__ int tsum[256];
    int t = threadIdx.x;
    const int CH = (NNODE + 255) / 256;   // 196
    int s0 = t * CH, s1 = min(s0 + CH, NNODE);
    int s = 0;
    for (int i = s0; i < s1; ++i) s += deg[i];
    tsum[t] = s;
    __syncthreads();
    #pragma unroll
    for (int off = 1; off < 256; off <<= 1) {
        int u = (t >= off) ? tsum[t - off] : 0;
        __syncthreads();
        tsum[t] += u;
        __syncthreads();
    }
    int run = tsum[t] - s;   // exclusive prefix of this thread's chunk
    for (int i = s0; i < s1; ++i) {
        int d = deg[i];
        base[i] = run;
        cursor[i] = run;
        run += d;
    }
    if (t == 0) base[NNODE] = NEDGE;
}

__global__ __launch_bounds__(256) void scatter_edges(const int* __restrict__ ei,
                                                     const float* __restrict__ ea,
                                                     int* __restrict__ cursor,
                                                     int2* __restrict__ se) {
    int e = blockIdx.x * 256 + threadIdx.x;
    if (e >= NEDGE) return;
    int d = ei[NEDGE + e];
    int i = atomicAdd(&cursor[d], 1);
    se[i] = make_int2(ei[e], __float_as_int(ea[e]));
}

// ---------------- node transform: 32 nodes/block, thread owns 4 cols x 8 nodes ----------
template<int K>
__global__ __launch_bounds__(256) void node_xform(const float* __restrict__ in,
                                                  const float* __restrict__ wl,
                                                  const float* __restrict__ wr,
                                                  float* __restrict__ xl,
                                                  float* __restrict__ xr) {
    __shared__ float xrow[32][K];
    int t = threadIdx.x;
    int n0 = blockIdx.x * 32;
    for (int idx = t; idx < 32 * (K / 4); idx += 256) {
        int row = idx / (K / 4), c4 = idx % (K / 4);
        float4 v = make_float4(0.f, 0.f, 0.f, 0.f);
        if (n0 + row < NNODE) v = ((const float4*)(in + (size_t)(n0 + row) * K))[c4];
        ((float4*)xrow[row])[c4] = v;
    }
    __syncthreads();
    int cg = t & 63, ns = t >> 6;
    const float* wsel = (cg < 32) ? wl : wr;
    float* osel = (cg < 32) ? xl : xr;
    int ccol = (cg & 31) * 4;
    const float* wp = wsel + ccol;
    const float* xbase = xrow[ns * 8];
    float4 acc[8];
    #pragma unroll
    for (int k = 0; k < 8; ++k) acc[k] = make_float4(0.f, 0.f, 0.f, 0.f);
    for (int i = 0; i < K; i += 4) {
        float4 w0 = *(const float4*)(wp + (size_t)(i + 0) * 128);
        float4 w1 = *(const float4*)(wp + (size_t)(i + 1) * 128);
        float4 w2 = *(const float4*)(wp + (size_t)(i + 2) * 128);
        float4 w3 = *(const float4*)(wp + (size_t)(i + 3) * 128);
        #pragma unroll
        for (int k = 0; k < 8; ++k) {
            float4 xv = *(const float4*)(xbase + (size_t)k * K + i);
            acc[k].x += xv.x * w0.x + xv.y * w1.x + xv.z * w2.x + xv.w * w3.x;
            acc[k].y += xv.x * w0.y + xv.y * w1.y + xv.z * w2.y + xv.w * w3.y;
            acc[k].z += xv.x * w0.z + xv.y * w1.z + xv.z * w2.z + xv.w * w3.z;
            acc[k].w += xv.x * w0.w + xv.y * w1.w + xv.z * w2.w + xv.w * w3.w;
        }
    }
    #pragma unroll
    for (int k = 0; k < 8; ++k) {
        int n = n0 + ns * 8 + k;
        if (n < NNODE) *(float4*)(osel + (size_t)n * 128 + ccol) = acc[k];
    }
}

// ---------------- fused GAT layer 1 (H=8, C=16): 4 edges/wave-iter, 8 ch/lane -------
// quarter q = ln>>4 handles edges i0+q, i0+q+4, ...; 2 lanes per head -> 1 shuffle
__global__ __launch_bounds__(256) void fused1(const int* __restrict__ base,
                                              const int2* __restrict__ se,
                                              const float* __restrict__ xl,
                                              const float* __restrict__ xr,
                                              const float* __restrict__ w1e,
                                              const float* __restrict__ att1,
                                              const float* __restrict__ b1,
                                              float* __restrict__ h1) {
    int t = threadIdx.x;
    int wv = t >> 6, ln = t & 63;
    int q = ln >> 4, sub = ln & 15;
    int n = blockIdx.x * 4 + wv;
    int ch = sub * 8;
    float4 xr0 = *(const float4*)(xr + (size_t)n * 128 + ch);
    float4 xr1 = *(const float4*)(xr + (size_t)n * 128 + ch + 4);
    float4 we0 = *(const float4*)(w1e + ch);
    float4 we1 = *(const float4*)(w1e + ch + 4);
    float4 at0 = *(const float4*)(att1 + ch);
    float4 at1 = *(const float4*)(att1 + ch + 4);
    int i0 = base[n], i1 = base[n + 1];
    float m = -1e30f, den = 0.f;
    float4 oa = make_float4(0.f, 0.f, 0.f, 0.f);
    float4 ob = make_float4(0.f, 0.f, 0.f, 0.f);
    int i = i0 + q;
    if (i < i1) {
        int2 r = se[i];
        const float* xp = xl + (size_t)r.x * 128 + ch;
        float4 xa = *(const float4*)xp, xb = *(const float4*)(xp + 4);
        float a = __int_as_float(r.y);
        for (i += 4; i < i1; i += 4) {
            int2 rn = se[i];
            const float* xpn = xl + (size_t)rn.x * 128 + ch;
            float4 nxa = *(const float4*)xpn, nxb = *(const float4*)(xpn + 4);
            float na = __int_as_float(rn.y);
            float part = part8(xa, xb, a, we0, we1, at0, at1, xr0, xr1);
            part += __shfl_xor(part, 1, 64);
            ONLINE_UPDATE(part, xa, xb);
            xa = nxa; xb = nxb; a = na;
        }
        float part = part8(xa, xb, a, we0, we1, at0, at1, xr0, xr1);
        part += __shfl_xor(part, 1, 64);
        ONLINE_UPDATE(part, xa, xb);
    }
    MERGE_STATE(16);
    MERGE_STATE(32);
    if (q == 0) {
        float inv = 1.f / (den + 1e-16f);
        float4 bv0 = *(const float4*)(b1 + ch);
        float4 bv1 = *(const float4*)(b1 + ch + 4);
        float4 ra, rb;
        ra.x = fmaxf(oa.x * inv + bv0.x, 0.f);
        ra.y = fmaxf(oa.y * inv + bv0.y, 0.f);
        ra.z = fmaxf(oa.z * inv + bv0.z, 0.f);
        ra.w = fmaxf(oa.w * inv + bv0.w, 0.f);
        rb.x = fmaxf(ob.x * inv + bv1.x, 0.f);
        rb.y = fmaxf(ob.y * inv + bv1.y, 0.f);
        rb.z = fmaxf(ob.z * inv + bv1.z, 0.f);
        rb.w = fmaxf(ob.w * inv + bv1.w, 0.f);
        *(float4*)(h1 + (size_t)n * 128 + ch) = ra;
        *(float4*)(h1 + (size_t)n * 128 + ch + 4) = rb;
    }
}

// ------- fused GAT layer 2 (H=2, C=64, mean) + classifier, one wave per node -------
// 8 lanes per head -> 3 shuffles; h2 row handed to classifier via LDS (never hits HBM)
__global__ __launch_bounds__(256) void fused2cls(const int* __restrict__ base,
                                                 const int2* __restrict__ se,
                                                 const float* __restrict__ xl,
                                                 const float* __restrict__ xr,
                                                 const float* __restrict__ w2e,
                                                 const float* __restrict__ att2,
                                                 const float* __restrict__ b2,
                                                 const float* __restrict__ wc,
                                                 const float* __restrict__ bc,
                                                 const float* __restrict__ lng,
                                                 const float* __restrict__ lnb,
                                                 const float* __restrict__ wrr,
                                                 const float* __restrict__ brr,
                                                 const float* __restrict__ lrg,
                                                 const float* __restrict__ lrb,
                                                 float* __restrict__ out) {
    __shared__ float rowH[4][64];
    __shared__ float rowB[4][64];
    int t = threadIdx.x;
    int wv = t >> 6, ln = t & 63;
    int q = ln >> 4, sub = ln & 15;
    int n = blockIdx.x * 4 + wv;
    int ch = sub * 8;
    float4 xr0 = *(const float4*)(xr + (size_t)n * 128 + ch);
    float4 xr1 = *(const float4*)(xr + (size_t)n * 128 + ch + 4);
    float4 we0 = *(const float4*)(w2e + ch);
    float4 we1 = *(const float4*)(w2e + ch + 4);
    float4 at0 = *(const float4*)(att2 + ch);
    float4 at1 = *(const float4*)(att2 + ch + 4);
    int i0 = base[n], i1 = base[n + 1];
    float m = -1e30f, den = 0.f;
    float4 oa = make_float4(0.f, 0.f, 0.f, 0.f);
    float4 ob = make_float4(0.f, 0.f, 0.f, 0.f);
    int i = i0 + q;
    if (i < i1) {
        int2 r = se[i];
        const float* xp = xl + (size_t)r.x * 128 + ch;
        float4 xa = *(const float4*)xp, xb = *(const float4*)(xp + 4);
        float a = __int_as_float(r.y);
        for (i += 4; i < i1; i += 4) {
            int2 rn = se[i];
            const float* xpn = xl + (size_t)rn.x * 128 + ch;
            float4 nxa = *(const float4*)xpn, nxb = *(const float4*)(xpn + 4);
            float na = __int_as_float(rn.y);
            float part = part8(xa, xb, a, we0, we1, at0, at1, xr0, xr1);
            part += __shfl_xor(part, 1, 64);
            part += __shfl_xor(part, 2, 64);
            part += __shfl_xor(part, 4, 64);
            ONLINE_UPDATE(part, xa, xb);
            xa = nxa; xb = nxb; a = na;
        }
        float part = part8(xa, xb, a, we0, we1, at0, at1, xr0, xr1);
        part += __shfl_xor(part, 1, 64);
        part += __shfl_xor(part, 2, 64);
        part += __shfl_xor(part, 4, 64);
        ONLINE_UPDATE(part, xa, xb);
    }
    MERGE_STATE(16);
    MERGE_STATE(32);
    // normalize, mean over 2 heads (partner lane sub^8 holds channel c+64)
    float inv = 1.f / (den + 1e-16f);
    float4 va, vb;
    va.x = oa.x * inv; va.y = oa.y * inv; va.z = oa.z * inv; va.w = oa.w * inv;
    vb.x = ob.x * inv; vb.y = ob.y * inv; vb.z = ob.z * inv; vb.w = ob.w * inv;
    float4 ua, ub;
    ua.x = __shfl_xor(va.x, 8, 64); ua.y = __shfl_xor(va.y, 8, 64);
    ua.z = __shfl_xor(va.z, 8, 64); ua.w = __shfl_xor(va.w, 8, 64);
    ub.x = __shfl_xor(vb.x, 8, 64); ub.y = __shfl_xor(vb.y, 8, 64);
    ub.z = __shfl_xor(vb.z, 8, 64); ub.w = __shfl_xor(vb.w, 8, 64);
    if (q == 0 && sub < 8) {
        int c = sub * 8;
        float4 bv0 = *(const float4*)(b2 + c);
        float4 bv1 = *(const float4*)(b2 + c + 4);
        float4 ra, rb;
        ra.x = fmaxf(0.5f * (va.x + ua.x) + bv0.x, 0.f);
        ra.y = fmaxf(0.5f * (va.y + ua.y) + bv0.y, 0.f);
        ra.z = fmaxf(0.5f * (va.z + ua.z) + bv0.z, 0.f);
        ra.w = fmaxf(0.5f * (va.w + ua.w) + bv0.w, 0.f);
        rb.x = fmaxf(0.5f * (vb.x + ub.x) + bv1.x, 0.f);
        rb.y = fmaxf(0.5f * (vb.y + ub.y) + bv1.y, 0.f);
        rb.z = fmaxf(0.5f * (vb.z + ub.z) + bv1.z, 0.f);
        rb.w = fmaxf(0.5f * (vb.w + ub.w) + bv1.w, 0.f);
        *(float4*)(&rowH[wv][c]) = ra;
        *(float4*)(&rowH[wv][c + 4]) = rb;
    }
    __syncthreads();
    // ---- classifier (per-wave matvecs + LN + GELU + residual) ----
    float acc = bc[ln];
    #pragma unroll 8
    for (int j = 0; j < 64; ++j) acc += rowH[wv][j] * wc[j * 64 + ln];
    float mu = wsum64(acc) * (1.f / 64.f);
    float dv = acc - mu;
    float var = wsum64(dv * dv) * (1.f / 64.f);
    float y = dv * rsqrtf(var + 1e-5f) * lng[ln] + lnb[ln];
    float g1 = gelu_exact(y);
    rowB[wv][ln] = g1;
    __syncthreads();
    float acc2 = brr[ln];
    #pragma unroll 8
    for (int j = 0; j < 64; ++j) acc2 += rowB[wv][j] * wrr[j * 64 + ln];
    float mu2 = wsum64(acc2) * (1.f / 64.f);
    float dv2 = acc2 - mu2;
    float var2 = wsum64(dv2 * dv2) * (1.f / 64.f);
    float y2 = dv2 * rsqrtf(var2 + 1e-5f) * lrg[ln] + lrb[ln];
    float g2 = gelu_exact(y2);
    out[(size_t)n * 64 + ln] = g1 + g2;
}

extern "C" void kernel_launch(void* const* d_in, const int* in_sizes, int n_in,
                              void* d_out, int out_size, void* d_ws, size_t ws_size,
                              hipStream_t stream) {
    const float* x    = (const float*)d_in[0];
    const int*   ei   = (const int*)d_in[1];
    const float* ea   = (const float*)d_in[2];
    const float* w1l  = (const float*)d_in[3];
    const float* w1r  = (const float*)d_in[4];
    const float* w1e  = (const float*)d_in[5];
    const float* att1 = (const float*)d_in[6];
    const float* b1   = (const float*)d_in[7];
    const float* w2l  = (const float*)d_in[8];
    const float* w2r  = (const float*)d_in[9];
    const float* w2e  = (const float*)d_in[10];
    const float* att2 = (const float*)d_in[11];
    const float* b2   = (const float*)d_in[12];
    const float* wc   = (const float*)d_in[13];
    const float* bc   = (const float*)d_in[14];
    const float* lng  = (const float*)d_in[15];
    const float* lnb  = (const float*)d_in[16];
    const float* wr   = (const float*)d_in[17];
    const float* br   = (const float*)d_in[18];
    const float* lrg  = (const float*)d_in[19];
    const float* lrb  = (const float*)d_in[20];

    float* ws = (float*)d_ws;
    const size_t N128 = (size_t)NNODE * 128;
    float* xl = ws;
    float* xr = xl + N128;
    float* h1 = xr + N128;
    int2*  se      = (int2*)(h1 + N128);      // NEDGE (8B aligned)
    int*   deg     = (int*)(se + NEDGE);
    int*   base    = deg + NNODE;             // NNODE+1
    int*   cursor  = base + NNODE + 1;

    const int EB  = NEDGE / 256;              // 3125
    const int NBX = (NNODE + 31) / 32;        // 1563
    const int NB4 = NNODE / 4;                // 12500

    // ---- CSR build (dst-sorted) ----
    fill_u32<<<NBLK, 256, 0, stream>>>((unsigned*)deg, 0u, NNODE);
    build_deg<<<EB, 256, 0, stream>>>(ei, deg);
    scan_all<<<1, 256, 0, stream>>>(deg, base, cursor);
    scatter_edges<<<EB, 256, 0, stream>>>(ei, ea, cursor, se);

    // ---- layer 1 ----
    node_xform<64><<<NBX, 256, 0, stream>>>(x, w1l, w1r, xl, xr);
    fused1<<<NB4, 256, 0, stream>>>(base, se, xl, xr, w1e, att1, b1, h1);

    // ---- layer 2 + classifier ----
    node_xform<128><<<NBX, 256, 0, stream>>>(h1, w2l, w2r, xl, xr);
    fused2cls<<<NB4, 256, 0, stream>>>(base, se, xl, xr, w2e, att2, b2,
                                       wc, bc, lng, lnb, wr, br, lrg, lrb,
                                       (float*)d_out);
}

// Round 8
// 451.965 us; speedup vs baseline: 1.0391x; 1.0391x over previous
//
#include <hip/hip_runtime.h>
#include <math.h>

#define NNODE 50000
#define NEDGE 800000
#define NBLK 196   // ceil(50000/256)

__device__ __forceinline__ float wsum64(float v) {
    #pragma unroll
    for (int m = 32; m >= 1; m >>= 1) v += __shfl_xor(v, m, 64);
    return v;
}

__device__ __forceinline__ float gelu_exact(float x) {
    return 0.5f * x * (1.0f + erff(x * 0.70710678118654752f));
}

__device__ __forceinline__ float lrelu(float z) { return z > 0.f ? z : 0.2f * z; }

// ---------------- utility ----------------
__global__ void fill_u32(unsigned* __restrict__ p, unsigned v, int n) {
    int i = blockIdx.x * blockDim.x + threadIdx.x;
    if (i < n) p[i] = v;
}

// ---------------- CSR build ----------------
__global__ __launch_bounds__(256) void build_deg(const int* __restrict__ ei, int* __restrict__ deg) {
    int e = blockIdx.x * 256 + threadIdx.x;
    if (e >= NEDGE) return;
    atomicAdd(&deg[ei[NEDGE + e]], 1);
}

// single-block full exclusive scan of deg[NNODE] -> base, cursor
__global__ __launch_bounds__(256) void scan_all(const int* __restrict__ deg,
                                                int* __restrict__ base,
                                                int* __restrict__ cursor) {
    __shared__ int tsum[256];
    int t = threadIdx.x;
    const int CH = (NNODE + 255) / 256;   // 196
    int s0 = t * CH, s1 = min(s0 + CH, NNODE);
    int s = 0;
    for (int i = s0; i < s1; ++i) s += deg[i];
    tsum[t] = s;
    __syncthreads();
    #pragma unroll
    for (int off = 1; off < 256; off <<= 1) {
        int u = (t >= off) ? tsum[t - off] : 0;
        __syncthreads();
        tsum[t] += u;
        __syncthreads();
    }
    int run = tsum[t] - s;   // exclusive prefix of this thread's chunk
    for (int i = s0; i < s1; ++i) {
        int d = deg[i];
        base[i] = run;
        cursor[i] = run;
        run += d;
    }
    if (t == 0) base[NNODE] = NEDGE;
}

__global__ __launch_bounds__(256) void scatter_edges(const int* __restrict__ ei,
                                                     const float* __restrict__ ea,
                                                     int* __restrict__ cursor,
                                                     int2* __restrict__ se) {
    int e = blockIdx.x * 256 + threadIdx.x;
    if (e >= NEDGE) return;
    int d = ei[NEDGE + e];
    int i = atomicAdd(&cursor[d], 1);
    se[i] = make_int2(ei[e], __float_as_int(ea[e]));
}

// ---------------- node transform: 32 nodes/block, thread owns 4 cols x 8 nodes ----------
template<int K>
__global__ __launch_bounds__(256) void node_xform(const float* __restrict__ in,
                                                  const float* __restrict__ wl,
                                                  const float* __restrict__ wr,
                                                  float* __restrict__ xl,
                                                  float* __restrict__ xr) {
    __shared__ float xrow[32][K];
    int t = threadIdx.x;
    int n0 = blockIdx.x * 32;
    for (int idx = t; idx < 32 * (K / 4); idx += 256) {
        int row = idx / (K / 4), c4 = idx % (K / 4);
        float4 v = make_float4(0.f, 0.f, 0.f, 0.f);
        if (n0 + row < NNODE) v = ((const float4*)(in + (size_t)(n0 + row) * K))[c4];
        ((float4*)xrow[row])[c4] = v;
    }
    __syncthreads();
    int cg = t & 63, ns = t >> 6;
    const float* wsel = (cg < 32) ? wl : wr;
    float* osel = (cg < 32) ? xl : xr;
    int ccol = (cg & 31) * 4;
    const float* wp = wsel + ccol;
    const float* xbase = xrow[ns * 8];
    float4 acc[8];
    #pragma unroll
    for (int k = 0; k < 8; ++k) acc[k] = make_float4(0.f, 0.f, 0.f, 0.f);
    for (int i = 0; i < K; i += 4) {
        float4 w0 = *(const float4*)(wp + (size_t)(i + 0) * 128);
        float4 w1 = *(const float4*)(wp + (size_t)(i + 1) * 128);
        float4 w2 = *(const float4*)(wp + (size_t)(i + 2) * 128);
        float4 w3 = *(const float4*)(wp + (size_t)(i + 3) * 128);
        #pragma unroll
        for (int k = 0; k < 8; ++k) {
            float4 xv = *(const float4*)(xbase + (size_t)k * K + i);
            acc[k].x += xv.x * w0.x + xv.y * w1.x + xv.z * w2.x + xv.w * w3.x;
            acc[k].y += xv.x * w0.y + xv.y * w1.y + xv.z * w2.y + xv.w * w3.y;
            acc[k].z += xv.x * w0.z + xv.y * w1.z + xv.z * w2.z + xv.w * w3.z;
            acc[k].w += xv.x * w0.w + xv.y * w1.w + xv.z * w2.w + xv.w * w3.w;
        }
    }
    #pragma unroll
    for (int k = 0; k < 8; ++k) {
        int n = n0 + ns * 8 + k;
        if (n < NNODE) *(float4*)(osel + (size_t)n * 128 + ccol) = acc[k];
    }
}

// ---------------- fused online-softmax GAT layer 1 (H=8, C=16) ----------------
// one wave per node; half-wave per alternating edge; lane owns 4 channels;
// branchless update, lookahead-1 (R5-proven structure)
__global__ __launch_bounds__(256) void fused1(const int* __restrict__ base,
                                              const int2* __restrict__ se,
                                              const float* __restrict__ xl,
                                              const float* __restrict__ xr,
                                              const float* __restrict__ w1e,
                                              const float* __restrict__ att1,
                                              const float* __restrict__ b1,
                                              float* __restrict__ h1) {
    int t = threadIdx.x;
    int wv = t >> 6, ln = t & 63;
    int half = ln >> 5, sub = ln & 31;
    int n = blockIdx.x * 4 + wv;
    int ch = sub * 4;
    float4 xrv = *(const float4*)(xr + (size_t)n * 128 + ch);
    float4 wev = *(const float4*)(w1e + ch);
    float4 atv = *(const float4*)(att1 + ch);
    int i0 = base[n], i1 = base[n + 1];
    float m = -1e30f, den = 0.f;
    float4 o = make_float4(0.f, 0.f, 0.f, 0.f);
    int i = i0 + half;
    if (i < i1) {
        int2 r = se[i];
        float4 xv = *(const float4*)(xl + (size_t)r.x * 128 + ch);
        float a = __int_as_float(r.y);
        for (i += 2; i < i1; i += 2) {
            int2 rn = se[i];
            float4 nxv = *(const float4*)(xl + (size_t)rn.x * 128 + ch);
            float na = __int_as_float(rn.y);
            float part = lrelu(fmaf(a, wev.x, xv.x + xrv.x)) * atv.x
                       + lrelu(fmaf(a, wev.y, xv.y + xrv.y)) * atv.y
                       + lrelu(fmaf(a, wev.z, xv.z + xrv.z)) * atv.z
                       + lrelu(fmaf(a, wev.w, xv.w + xrv.w)) * atv.w;
            part += __shfl_xor(part, 1, 64);
            part += __shfl_xor(part, 2, 64);
            float mn = fmaxf(m, part);
            float sc = __expf(m - mn);
            float p  = __expf(part - mn);
            den = den * sc + p;
            o.x = o.x * sc + p * xv.x;
            o.y = o.y * sc + p * xv.y;
            o.z = o.z * sc + p * xv.z;
            o.w = o.w * sc + p * xv.w;
            m = mn;
            xv = nxv; a = na;
        }
        float part = lrelu(fmaf(a, wev.x, xv.x + xrv.x)) * atv.x
                   + lrelu(fmaf(a, wev.y, xv.y + xrv.y)) * atv.y
                   + lrelu(fmaf(a, wev.z, xv.z + xrv.z)) * atv.z
                   + lrelu(fmaf(a, wev.w, xv.w + xrv.w)) * atv.w;
        part += __shfl_xor(part, 1, 64);
        part += __shfl_xor(part, 2, 64);
        float mn = fmaxf(m, part);
        float sc = __expf(m - mn);
        float p  = __expf(part - mn);
        den = den * sc + p;
        o.x = o.x * sc + p * xv.x;
        o.y = o.y * sc + p * xv.y;
        o.z = o.z * sc + p * xv.z;
        o.w = o.w * sc + p * xv.w;
        m = mn;
    }
    float m2   = __shfl_xor(m, 32, 64);
    float den2 = __shfl_xor(den, 32, 64);
    float4 o2;
    o2.x = __shfl_xor(o.x, 32, 64);
    o2.y = __shfl_xor(o.y, 32, 64);
    o2.z = __shfl_xor(o.z, 32, 64);
    o2.w = __shfl_xor(o.w, 32, 64);
    float mn = fmaxf(m, m2);
    float s1 = __expf(m - mn), s2 = __expf(m2 - mn);
    den = den * s1 + den2 * s2;
    float inv = 1.f / (den + 1e-16f);
    if (half == 0) {
        float4 bv = *(const float4*)(b1 + ch);
        float4 res;
        res.x = fmaxf((o.x * s1 + o2.x * s2) * inv + bv.x, 0.f);
        res.y = fmaxf((o.y * s1 + o2.y * s2) * inv + bv.y, 0.f);
        res.z = fmaxf((o.z * s1 + o2.z * s2) * inv + bv.z, 0.f);
        res.w = fmaxf((o.w * s1 + o2.w * s2) * inv + bv.w, 0.f);
        *(float4*)(h1 + (size_t)n * 128 + ch) = res;
    }
}

// ------- fused GAT layer 2 (H=2, C=64, mean) + classifier tail (R5 loop + LDS handoff) ---
__global__ __launch_bounds__(256) void fused2cls(const int* __restrict__ base,
                                                 const int2* __restrict__ se,
                                                 const float* __restrict__ xl,
                                                 const float* __restrict__ xr,
                                                 const float* __restrict__ w2e,
                                                 const float* __restrict__ att2,
                                                 const float* __restrict__ b2,
                                                 const float* __restrict__ wc,
                                                 const float* __restrict__ bc,
                                                 const float* __restrict__ lng,
                                                 const float* __restrict__ lnb,
                                                 const float* __restrict__ wrr,
                                                 const float* __restrict__ brr,
                                                 const float* __restrict__ lrg,
                                                 const float* __restrict__ lrb,
                                                 float* __restrict__ out) {
    __shared__ float rowH[4][64];
    __shared__ float rowB[4][64];
    int t = threadIdx.x;
    int wv = t >> 6, ln = t & 63;
    int half = ln >> 5, sub = ln & 31;
    int n = blockIdx.x * 4 + wv;
    int ch = sub * 4;
    float4 xrv = *(const float4*)(xr + (size_t)n * 128 + ch);
    float4 wev = *(const float4*)(w2e + ch);
    float4 atv = *(const float4*)(att2 + ch);
    int i0 = base[n], i1 = base[n + 1];
    float m = -1e30f, den = 0.f;
    float4 o = make_float4(0.f, 0.f, 0.f, 0.f);
    int i = i0 + half;
    if (i < i1) {
        int2 r = se[i];
        float4 xv = *(const float4*)(xl + (size_t)r.x * 128 + ch);
        float a = __int_as_float(r.y);
        for (i += 2; i < i1; i += 2) {
            int2 rn = se[i];
            float4 nxv = *(const float4*)(xl + (size_t)rn.x * 128 + ch);
            float na = __int_as_float(rn.y);
            float part = lrelu(fmaf(a, wev.x, xv.x + xrv.x)) * atv.x
                       + lrelu(fmaf(a, wev.y, xv.y + xrv.y)) * atv.y
                       + lrelu(fmaf(a, wev.z, xv.z + xrv.z)) * atv.z
                       + lrelu(fmaf(a, wev.w, xv.w + xrv.w)) * atv.w;
            part += __shfl_xor(part, 1, 64);
            part += __shfl_xor(part, 2, 64);
            part += __shfl_xor(part, 4, 64);
            part += __shfl_xor(part, 8, 64);
            float mn = fmaxf(m, part);
            float sc = __expf(m - mn);
            float p  = __expf(part - mn);
            den = den * sc + p;
            o.x = o.x * sc + p * xv.x;
            o.y = o.y * sc + p * xv.y;
            o.z = o.z * sc + p * xv.z;
            o.w = o.w * sc + p * xv.w;
            m = mn;
            xv = nxv; a = na;
        }
        float part = lrelu(fmaf(a, wev.x, xv.x + xrv.x)) * atv.x
                   + lrelu(fmaf(a, wev.y, xv.y + xrv.y)) * atv.y
                   + lrelu(fmaf(a, wev.z, xv.z + xrv.z)) * atv.z
                   + lrelu(fmaf(a, wev.w, xv.w + xrv.w)) * atv.w;
        part += __shfl_xor(part, 1, 64);
        part += __shfl_xor(part, 2, 64);
        part += __shfl_xor(part, 4, 64);
        part += __shfl_xor(part, 8, 64);
        float mn = fmaxf(m, part);
        float sc = __expf(m - mn);
        float p  = __expf(part - mn);
        den = den * sc + p;
        o.x = o.x * sc + p * xv.x;
        o.y = o.y * sc + p * xv.y;
        o.z = o.z * sc + p * xv.z;
        o.w = o.w * sc + p * xv.w;
        m = mn;
    }
    float m2   = __shfl_xor(m, 32, 64);
    float den2 = __shfl_xor(den, 32, 64);
    float4 o2;
    o2.x = __shfl_xor(o.x, 32, 64);
    o2.y = __shfl_xor(o.y, 32, 64);
    o2.z = __shfl_xor(o.z, 32, 64);
    o2.w = __shfl_xor(o.w, 32, 64);
    float mn = fmaxf(m, m2);
    float s1 = __expf(m - mn), s2 = __expf(m2 - mn);
    den = den * s1 + den2 * s2;
    float inv = 1.f / (den + 1e-16f);
    float4 v;
    v.x = (o.x * s1 + o2.x * s2) * inv;
    v.y = (o.y * s1 + o2.y * s2) * inv;
    v.z = (o.z * s1 + o2.z * s2) * inv;
    v.w = (o.w * s1 + o2.w * s2) * inv;
    // mean over the two heads: partner lane sub ^ 16 (head0 ch c <-> head1 ch c+64)
    float4 u;
    u.x = __shfl_xor(v.x, 16, 64);
    u.y = __shfl_xor(v.y, 16, 64);
    u.z = __shfl_xor(v.z, 16, 64);
    u.w = __shfl_xor(v.w, 16, 64);
    if (half == 0 && sub < 16) {
        float4 bv = *(const float4*)(b2 + ch);
        float4 res;
        res.x = fmaxf(0.5f * (v.x + u.x) + bv.x, 0.f);
        res.y = fmaxf(0.5f * (v.y + u.y) + bv.y, 0.f);
        res.z = fmaxf(0.5f * (v.z + u.z) + bv.z, 0.f);
        res.w = fmaxf(0.5f * (v.w + u.w) + bv.w, 0.f);
        *(float4*)(&rowH[wv][ch]) = res;
    }
    __syncthreads();
    // ---- classifier (per-wave matvecs + LN + GELU + residual) ----
    float acc = bc[ln];
    #pragma unroll 8
    for (int j = 0; j < 64; ++j) acc += rowH[wv][j] * wc[j * 64 + ln];
    float mu = wsum64(acc) * (1.f / 64.f);
    float dv = acc - mu;
    float var = wsum64(dv * dv) * (1.f / 64.f);
    float y = dv * rsqrtf(var + 1e-5f) * lng[ln] + lnb[ln];
    float g1 = gelu_exact(y);
    rowB[wv][ln] = g1;
    __syncthreads();
    float acc2 = brr[ln];
    #pragma unroll 8
    for (int j = 0; j < 64; ++j) acc2 += rowB[wv][j] * wrr[j * 64 + ln];
    float mu2 = wsum64(acc2) * (1.f / 64.f);
    float dv2 = acc2 - mu2;
    float var2 = wsum64(dv2 * dv2) * (1.f / 64.f);
    float y2 = dv2 * rsqrtf(var2 + 1e-5f) * lrg[ln] + lrb[ln];
    float g2 = gelu_exact(y2);
    out[(size_t)n * 64 + ln] = g1 + g2;
}

extern "C" void kernel_launch(void* const* d_in, const int* in_sizes, int n_in,
                              void* d_out, int out_size, void* d_ws, size_t ws_size,
                              hipStream_t stream) {
    const float* x    = (const float*)d_in[0];
    const int*   ei   = (const int*)d_in[1];
    const float* ea   = (const float*)d_in[2];
    const float* w1l  = (const float*)d_in[3];
    const float* w1r  = (const float*)d_in[4];
    const float* w1e  = (const float*)d_in[5];
    const float* att1 = (const float*)d_in[6];
    const float* b1   = (const float*)d_in[7];
    const float* w2l  = (const float*)d_in[8];
    const float* w2r  = (const float*)d_in[9];
    const float* w2e  = (const float*)d_in[10];
    const float* att2 = (const float*)d_in[11];
    const float* b2   = (const float*)d_in[12];
    const float* wc   = (const float*)d_in[13];
    const float* bc   = (const float*)d_in[14];
    const float* lng  = (const float*)d_in[15];
    const float* lnb  = (const float*)d_in[16];
    const float* wr   = (const float*)d_in[17];
    const float* br   = (const float*)d_in[18];
    const float* lrg  = (const float*)d_in[19];
    const float* lrb  = (const float*)d_in[20];

    float* ws = (float*)d_ws;
    const size_t N128 = (size_t)NNODE * 128;
    float* xl = ws;
    float* xr = xl + N128;
    float* h1 = xr + N128;
    int2*  se      = (int2*)(h1 + N128);      // NEDGE (8B aligned)
    int*   deg     = (int*)(se + NEDGE);
    int*   base    = deg + NNODE;             // NNODE+1
    int*   cursor  = base + NNODE + 1;

    const int EB  = NEDGE / 256;              // 3125
    const int NBX = (NNODE + 31) / 32;        // 1563
    const int NB4 = NNODE / 4;                // 12500

    // ---- CSR build (dst-sorted) ----
    fill_u32<<<NBLK, 256, 0, stream>>>((unsigned*)deg, 0u, NNODE);
    build_deg<<<EB, 256, 0, stream>>>(ei, deg);
    scan_all<<<1, 256, 0, stream>>>(deg, base, cursor);
    scatter_edges<<<EB, 256, 0, stream>>>(ei, ea, cursor, se);

    // ---- layer 1 ----
    node_xform<64><<<NBX, 256, 0, stream>>>(x, w1l, w1r, xl, xr);
    fused1<<<NB4, 256, 0, stream>>>(base, se, xl, xr, w1e, att1, b1, h1);

    // ---- layer 2 + classifier ----
    node_xform<128><<<NBX, 256, 0, stream>>>(h1, w2l, w2r, xl, xr);
    fused2cls<<<NB4, 256, 0, stream>>>(base, se, xl, xr, w2e, att2, b2,
                                       wc, bc, lng, lnb, wr, br, lrg, lrb,
                                       (float*)d_out);
}

// Round 9
// 340.808 us; speedup vs baseline: 1.3780x; 1.3262x over previous
//
#include <hip/hip_runtime.h>
#include <math.h>

#define NNODE 50000
#define NEDGE 800000
#define NBLK 196   // ceil(50000/256)

__device__ __forceinline__ float wsum64(float v) {
    #pragma unroll
    for (int m = 32; m >= 1; m >>= 1) v += __shfl_xor(v, m, 64);
    return v;
}

__device__ __forceinline__ float gelu_exact(float x) {
    return 0.5f * x * (1.0f + erff(x * 0.70710678118654752f));
}

__device__ __forceinline__ float lrelu(float z) { return z > 0.f ? z : 0.2f * z; }

// ---------------- utility ----------------
__global__ void fill_u32(unsigned* __restrict__ p, unsigned v, int n) {
    int i = blockIdx.x * blockDim.x + threadIdx.x;
    if (i < n) p[i] = v;
}

// ---------------- CSR build ----------------
__global__ __launch_bounds__(256) void build_deg(const int* __restrict__ ei, int* __restrict__ deg) {
    int e = blockIdx.x * 256 + threadIdx.x;
    if (e >= NEDGE) return;
    atomicAdd(&deg[ei[NEDGE + e]], 1);
}

// three-phase parallel exclusive scan (R5-proven, ~10 us total)
__global__ __launch_bounds__(256) void scan1(const int* __restrict__ deg,
                                             int* __restrict__ partial,
                                             int* __restrict__ bsum) {
    __shared__ int tmp[256];
    int t = threadIdx.x;
    int gid = blockIdx.x * 256 + t;
    int v = (gid < NNODE) ? deg[gid] : 0;
    tmp[t] = v;
    __syncthreads();
    #pragma unroll
    for (int off = 1; off < 256; off <<= 1) {
        int u = (t >= off) ? tmp[t - off] : 0;
        __syncthreads();
        tmp[t] += u;
        __syncthreads();
    }
    if (gid < NNODE) partial[gid] = tmp[t] - v;   // exclusive
    if (t == 255) bsum[blockIdx.x] = tmp[255];
}

__global__ __launch_bounds__(256) void scan2(int* __restrict__ bsum, int* __restrict__ boff) {
    __shared__ int tmp[256];
    int t = threadIdx.x;
    int v = (t < NBLK) ? bsum[t] : 0;
    tmp[t] = v;
    __syncthreads();
    #pragma unroll
    for (int off = 1; off < 256; off <<= 1) {
        int u = (t >= off) ? tmp[t - off] : 0;
        __syncthreads();
        tmp[t] += u;
        __syncthreads();
    }
    if (t < NBLK) boff[t] = tmp[t] - v;      // exclusive
}

__global__ __launch_bounds__(256) void scan3(const int* __restrict__ partial,
                                             const int* __restrict__ boff,
                                             int* __restrict__ base,
                                             int* __restrict__ cursor) {
    int gid = blockIdx.x * 256 + threadIdx.x;
    if (gid < NNODE) {
        int b = partial[gid] + boff[blockIdx.x];
        base[gid] = b;
        cursor[gid] = b;
    }
    if (gid == 0) base[NNODE] = NEDGE;
}

__global__ __launch_bounds__(256) void scatter_edges(const int* __restrict__ ei,
                                                     const float* __restrict__ ea,
                                                     int* __restrict__ cursor,
                                                     int2* __restrict__ se) {
    int e = blockIdx.x * 256 + threadIdx.x;
    if (e >= NEDGE) return;
    int d = ei[NEDGE + e];
    int i = atomicAdd(&cursor[d], 1);
    se[i] = make_int2(ei[e], __float_as_int(ea[e]));
}

// ---------------- node transform: 32 nodes/block, thread owns 4 cols x 8 nodes ----------
template<int K>
__global__ __launch_bounds__(256) void node_xform(const float* __restrict__ in,
                                                  const float* __restrict__ wl,
                                                  const float* __restrict__ wr,
                                                  float* __restrict__ xl,
                                                  float* __restrict__ xr) {
    __shared__ float xrow[32][K];
    int t = threadIdx.x;
    int n0 = blockIdx.x * 32;
    for (int idx = t; idx < 32 * (K / 4); idx += 256) {
        int row = idx / (K / 4), c4 = idx % (K / 4);
        float4 v = make_float4(0.f, 0.f, 0.f, 0.f);
        if (n0 + row < NNODE) v = ((const float4*)(in + (size_t)(n0 + row) * K))[c4];
        ((float4*)xrow[row])[c4] = v;
    }
    __syncthreads();
    int cg = t & 63, ns = t >> 6;
    const float* wsel = (cg < 32) ? wl : wr;
    float* osel = (cg < 32) ? xl : xr;
    int ccol = (cg & 31) * 4;
    const float* wp = wsel + ccol;
    const float* xbase = xrow[ns * 8];
    float4 acc[8];
    #pragma unroll
    for (int k = 0; k < 8; ++k) acc[k] = make_float4(0.f, 0.f, 0.f, 0.f);
    for (int i = 0; i < K; i += 4) {
        float4 w0 = *(const float4*)(wp + (size_t)(i + 0) * 128);
        float4 w1 = *(const float4*)(wp + (size_t)(i + 1) * 128);
        float4 w2 = *(const float4*)(wp + (size_t)(i + 2) * 128);
        float4 w3 = *(const float4*)(wp + (size_t)(i + 3) * 128);
        #pragma unroll
        for (int k = 0; k < 8; ++k) {
            float4 xv = *(const float4*)(xbase + (size_t)k * K + i);
            acc[k].x += xv.x * w0.x + xv.y * w1.x + xv.z * w2.x + xv.w * w3.x;
            acc[k].y += xv.x * w0.y + xv.y * w1.y + xv.z * w2.y + xv.w * w3.y;
            acc[k].z += xv.x * w0.z + xv.y * w1.z + xv.z * w2.z + xv.w * w3.z;
            acc[k].w += xv.x * w0.w + xv.y * w1.w + xv.z * w2.w + xv.w * w3.w;
        }
    }
    #pragma unroll
    for (int k = 0; k < 8; ++k) {
        int n = n0 + ns * 8 + k;
        if (n < NNODE) *(float4*)(osel + (size_t)n * 128 + ccol) = acc[k];
    }
}

// ---------------- fused online-softmax GAT layer 1 (H=8, C=16) ----------------
__global__ __launch_bounds__(256) void fused1(const int* __restrict__ base,
                                              const int2* __restrict__ se,
                                              const float* __restrict__ xl,
                                              const float* __restrict__ xr,
                                              const float* __restrict__ w1e,
                                              const float* __restrict__ att1,
                                              const float* __restrict__ b1,
                                              float* __restrict__ h1) {
    int t = threadIdx.x;
    int wv = t >> 6, ln = t & 63;
    int half = ln >> 5, sub = ln & 31;
    int n = blockIdx.x * 4 + wv;
    int ch = sub * 4;
    float4 xrv = *(const float4*)(xr + (size_t)n * 128 + ch);
    float4 wev = *(const float4*)(w1e + ch);
    float4 atv = *(const float4*)(att1 + ch);
    int i0 = base[n], i1 = base[n + 1];
    float m = -1e30f, den = 0.f;
    float4 o = make_float4(0.f, 0.f, 0.f, 0.f);
    int i = i0 + half;
    if (i < i1) {
        int2 r = se[i];
        float4 xv = *(const float4*)(xl + (size_t)r.x * 128 + ch);
        float a = __int_as_float(r.y);
        for (i += 2; i < i1; i += 2) {
            int2 rn = se[i];
            float4 nxv = *(const float4*)(xl + (size_t)rn.x * 128 + ch);
            float na = __int_as_float(rn.y);
            float part = lrelu(fmaf(a, wev.x, xv.x + xrv.x)) * atv.x
                       + lrelu(fmaf(a, wev.y, xv.y + xrv.y)) * atv.y
                       + lrelu(fmaf(a, wev.z, xv.z + xrv.z)) * atv.z
                       + lrelu(fmaf(a, wev.w, xv.w + xrv.w)) * atv.w;
            part += __shfl_xor(part, 1, 64);
            part += __shfl_xor(part, 2, 64);
            float mn = fmaxf(m, part);
            float sc = __expf(m - mn);
            float p  = __expf(part - mn);
            den = den * sc + p;
            o.x = o.x * sc + p * xv.x;
            o.y = o.y * sc + p * xv.y;
            o.z = o.z * sc + p * xv.z;
            o.w = o.w * sc + p * xv.w;
            m = mn;
            xv = nxv; a = na;
        }
        float part = lrelu(fmaf(a, wev.x, xv.x + xrv.x)) * atv.x
                   + lrelu(fmaf(a, wev.y, xv.y + xrv.y)) * atv.y
                   + lrelu(fmaf(a, wev.z, xv.z + xrv.z)) * atv.z
                   + lrelu(fmaf(a, wev.w, xv.w + xrv.w)) * atv.w;
        part += __shfl_xor(part, 1, 64);
        part += __shfl_xor(part, 2, 64);
        float mn = fmaxf(m, part);
        float sc = __expf(m - mn);
        float p  = __expf(part - mn);
        den = den * sc + p;
        o.x = o.x * sc + p * xv.x;
        o.y = o.y * sc + p * xv.y;
        o.z = o.z * sc + p * xv.z;
        o.w = o.w * sc + p * xv.w;
        m = mn;
    }
    float m2   = __shfl_xor(m, 32, 64);
    float den2 = __shfl_xor(den, 32, 64);
    float4 o2;
    o2.x = __shfl_xor(o.x, 32, 64);
    o2.y = __shfl_xor(o.y, 32, 64);
    o2.z = __shfl_xor(o.z, 32, 64);
    o2.w = __shfl_xor(o.w, 32, 64);
    float mn = fmaxf(m, m2);
    float s1 = __expf(m - mn), s2 = __expf(m2 - mn);
    den = den * s1 + den2 * s2;
    float inv = 1.f / (den + 1e-16f);
    if (half == 0) {
        float4 bv = *(const float4*)(b1 + ch);
        float4 res;
        res.x = fmaxf((o.x * s1 + o2.x * s2) * inv + bv.x, 0.f);
        res.y = fmaxf((o.y * s1 + o2.y * s2) * inv + bv.y, 0.f);
        res.z = fmaxf((o.z * s1 + o2.z * s2) * inv + bv.z, 0.f);
        res.w = fmaxf((o.w * s1 + o2.w * s2) * inv + bv.w, 0.f);
        *(float4*)(h1 + (size_t)n * 128 + ch) = res;
    }
}

// ------- fused GAT layer 2 (H=2, C=64, mean) + classifier tail (LDS handoff) ---
__global__ __launch_bounds__(256) void fused2cls(const int* __restrict__ base,
                                                 const int2* __restrict__ se,
                                                 const float* __restrict__ xl,
                                                 const float* __restrict__ xr,
                                                 const float* __restrict__ w2e,
                                                 const float* __restrict__ att2,
                                                 const float* __restrict__ b2,
                                                 const float* __restrict__ wc,
                                                 const float* __restrict__ bc,
                                                 const float* __restrict__ lng,
                                                 const float* __restrict__ lnb,
                                                 const float* __restrict__ wrr,
                                                 const float* __restrict__ brr,
                                                 const float* __restrict__ lrg,
                                                 const float* __restrict__ lrb,
                                                 float* __restrict__ out) {
    __shared__ float rowH[4][64];
    __shared__ float rowB[4][64];
    int t = threadIdx.x;
    int wv = t >> 6, ln = t & 63;
    int half = ln >> 5, sub = ln & 31;
    int n = blockIdx.x * 4 + wv;
    int ch = sub * 4;
    float4 xrv = *(const float4*)(xr + (size_t)n * 128 + ch);
    float4 wev = *(const float4*)(w2e + ch);
    float4 atv = *(const float4*)(att2 + ch);
    int i0 = base[n], i1 = base[n + 1];
    float m = -1e30f, den = 0.f;
    float4 o = make_float4(0.f, 0.f, 0.f, 0.f);
    int i = i0 + half;
    if (i < i1) {
        int2 r = se[i];
        float4 xv = *(const float4*)(xl + (size_t)r.x * 128 + ch);
        float a = __int_as_float(r.y);
        for (i += 2; i < i1; i += 2) {
            int2 rn = se[i];
            float4 nxv = *(const float4*)(xl + (size_t)rn.x * 128 + ch);
            float na = __int_as_float(rn.y);
            float part = lrelu(fmaf(a, wev.x, xv.x + xrv.x)) * atv.x
                       + lrelu(fmaf(a, wev.y, xv.y + xrv.y)) * atv.y
                       + lrelu(fmaf(a, wev.z, xv.z + xrv.z)) * atv.z
                       + lrelu(fmaf(a, wev.w, xv.w + xrv.w)) * atv.w;
            part += __shfl_xor(part, 1, 64);
            part += __shfl_xor(part, 2, 64);
            part += __shfl_xor(part, 4, 64);
            part += __shfl_xor(part, 8, 64);
            float mn = fmaxf(m, part);
            float sc = __expf(m - mn);
            float p  = __expf(part - mn);
            den = den * sc + p;
            o.x = o.x * sc + p * xv.x;
            o.y = o.y * sc + p * xv.y;
            o.z = o.z * sc + p * xv.z;
            o.w = o.w * sc + p * xv.w;
            m = mn;
            xv = nxv; a = na;
        }
        float part = lrelu(fmaf(a, wev.x, xv.x + xrv.x)) * atv.x
                   + lrelu(fmaf(a, wev.y, xv.y + xrv.y)) * atv.y
                   + lrelu(fmaf(a, wev.z, xv.z + xrv.z)) * atv.z
                   + lrelu(fmaf(a, wev.w, xv.w + xrv.w)) * atv.w;
        part += __shfl_xor(part, 1, 64);
        part += __shfl_xor(part, 2, 64);
        part += __shfl_xor(part, 4, 64);
        part += __shfl_xor(part, 8, 64);
        float mn = fmaxf(m, part);
        float sc = __expf(m - mn);
        float p  = __expf(part - mn);
        den = den * sc + p;
        o.x = o.x * sc + p * xv.x;
        o.y = o.y * sc + p * xv.y;
        o.z = o.z * sc + p * xv.z;
        o.w = o.w * sc + p * xv.w;
        m = mn;
    }
    float m2   = __shfl_xor(m, 32, 64);
    float den2 = __shfl_xor(den, 32, 64);
    float4 o2;
    o2.x = __shfl_xor(o.x, 32, 64);
    o2.y = __shfl_xor(o.y, 32, 64);
    o2.z = __shfl_xor(o.z, 32, 64);
    o2.w = __shfl_xor(o.w, 32, 64);
    float mn = fmaxf(m, m2);
    float s1 = __expf(m - mn), s2 = __expf(m2 - mn);
    den = den * s1 + den2 * s2;
    float inv = 1.f / (den + 1e-16f);
    float4 v;
    v.x = (o.x * s1 + o2.x * s2) * inv;
    v.y = (o.y * s1 + o2.y * s2) * inv;
    v.z = (o.z * s1 + o2.z * s2) * inv;
    v.w = (o.w * s1 + o2.w * s2) * inv;
    float4 u;
    u.x = __shfl_xor(v.x, 16, 64);
    u.y = __shfl_xor(v.y, 16, 64);
    u.z = __shfl_xor(v.z, 16, 64);
    u.w = __shfl_xor(v.w, 16, 64);
    if (half == 0 && sub < 16) {
        float4 bv = *(const float4*)(b2 + ch);
        float4 res;
        res.x = fmaxf(0.5f * (v.x + u.x) + bv.x, 0.f);
        res.y = fmaxf(0.5f * (v.y + u.y) + bv.y, 0.f);
        res.z = fmaxf(0.5f * (v.z + u.z) + bv.z, 0.f);
        res.w = fmaxf(0.5f * (v.w + u.w) + bv.w, 0.f);
        *(float4*)(&rowH[wv][ch]) = res;
    }
    __syncthreads();
    // ---- classifier (per-wave matvecs + LN + GELU + residual) ----
    float acc = bc[ln];
    #pragma unroll 8
    for (int j = 0; j < 64; ++j) acc += rowH[wv][j] * wc[j * 64 + ln];
    float mu = wsum64(acc) * (1.f / 64.f);
    float dv = acc - mu;
    float var = wsum64(dv * dv) * (1.f / 64.f);
    float y = dv * rsqrtf(var + 1e-5f) * lng[ln] + lnb[ln];
    float g1 = gelu_exact(y);
    rowB[wv][ln] = g1;
    __syncthreads();
    float acc2 = brr[ln];
    #pragma unroll 8
    for (int j = 0; j < 64; ++j) acc2 += rowB[wv][j] * wrr[j * 64 + ln];
    float mu2 = wsum64(acc2) * (1.f / 64.f);
    float dv2 = acc2 - mu2;
    float var2 = wsum64(dv2 * dv2) * (1.f / 64.f);
    float y2 = dv2 * rsqrtf(var2 + 1e-5f) * lrg[ln] + lrb[ln];
    float g2 = gelu_exact(y2);
    out[(size_t)n * 64 + ln] = g1 + g2;
}

extern "C" void kernel_launch(void* const* d_in, const int* in_sizes, int n_in,
                              void* d_out, int out_size, void* d_ws, size_t ws_size,
                              hipStream_t stream) {
    const float* x    = (const float*)d_in[0];
    const int*   ei   = (const int*)d_in[1];
    const float* ea   = (const float*)d_in[2];
    const float* w1l  = (const float*)d_in[3];
    const float* w1r  = (const float*)d_in[4];
    const float* w1e  = (const float*)d_in[5];
    const float* att1 = (const float*)d_in[6];
    const float* b1   = (const float*)d_in[7];
    const float* w2l  = (const float*)d_in[8];
    const float* w2r  = (const float*)d_in[9];
    const float* w2e  = (const float*)d_in[10];
    const float* att2 = (const float*)d_in[11];
    const float* b2   = (const float*)d_in[12];
    const float* wc   = (const float*)d_in[13];
    const float* bc   = (const float*)d_in[14];
    const float* lng  = (const float*)d_in[15];
    const float* lnb  = (const float*)d_in[16];
    const float* wr   = (const float*)d_in[17];
    const float* br   = (const float*)d_in[18];
    const float* lrg  = (const float*)d_in[19];
    const float* lrb  = (const float*)d_in[20];

    float* ws = (float*)d_ws;
    const size_t N128 = (size_t)NNODE * 128;
    float* xl = ws;
    float* xr = xl + N128;
    float* h1 = xr + N128;
    int2*  se      = (int2*)(h1 + N128);      // NEDGE (8B aligned)
    int*   deg     = (int*)(se + NEDGE);
    int*   partial = deg + NNODE;
    int*   base    = partial + NNODE;         // NNODE+1
    int*   cursor  = base + NNODE + 1;
    int*   bsum    = cursor + NNODE;          // 256
    int*   boff    = bsum + 256;              // 256

    const int EB  = NEDGE / 256;              // 3125
    const int NBX = (NNODE + 31) / 32;        // 1563
    const int NB4 = NNODE / 4;                // 12500

    // ---- CSR build (dst-sorted) ----
    fill_u32<<<NBLK, 256, 0, stream>>>((unsigned*)deg, 0u, NNODE);
    build_deg<<<EB, 256, 0, stream>>>(ei, deg);
    scan1<<<NBLK, 256, 0, stream>>>(deg, partial, bsum);
    scan2<<<1, 256, 0, stream>>>(bsum, boff);
    scan3<<<NBLK, 256, 0, stream>>>(partial, boff, base, cursor);
    scatter_edges<<<EB, 256, 0, stream>>>(ei, ea, cursor, se);

    // ---- layer 1 ----
    node_xform<64><<<NBX, 256, 0, stream>>>(x, w1l, w1r, xl, xr);
    fused1<<<NB4, 256, 0, stream>>>(base, se, xl, xr, w1e, att1, b1, h1);

    // ---- layer 2 + classifier ----
    node_xform<128><<<NBX, 256, 0, stream>>>(h1, w2l, w2r, xl, xr);
    fused2cls<<<NB4, 256, 0, stream>>>(base, se, xl, xr, w2e, att2, b2,
                                       wc, bc, lng, lnb, wr, br, lrg, lrb,
                                       (float*)d_out);
}